// Round 1
// baseline (308.233 us; speedup 1.0000x reference)
//
#include <hip/hip_runtime.h>

#define TX 64
#define TY 32
#define HALO_W (TX + 2)          // 66
#define HALO_H (TY + 2)          // 34
#define NTX (1024 / TX)          // 16
#define NTY (1024 / TY)          // 32
#define NBATCH 16
#define NTILES (NTX * NTY * NBATCH)  // 8192
#define NBLOCKS 2048

__global__ void lbp_zero_hist(unsigned* __restrict__ g_hist) {
    g_hist[threadIdx.x] = 0u;
}

__global__ __launch_bounds__(256) void lbp_hist_kernel(
        const float* __restrict__ img, unsigned* __restrict__ g_hist) {
    __shared__ float tile[HALO_H][HALO_W];
    __shared__ unsigned s_hist[256];
    const int tid = threadIdx.x;
    s_hist[tid] = 0u;

    for (int t = blockIdx.x; t < NTILES; t += NBLOCKS) {
        const int bx  = t % NTX;
        const int rem = t / NTX;
        const int by  = rem % NTY;
        const int b   = rem / NTY;
        const int x0 = bx * TX - 1;
        const int y0 = by * TY - 1;
        const float* imgb = img + (size_t)b * 3u * 1024u * 1024u;

        __syncthreads();  // tile reuse across grid-stride iterations
        for (int idx = tid; idx < HALO_H * HALO_W; idx += 256) {
            const int ly = idx / HALO_W;
            const int lx = idx - ly * HALO_W;
            const int gy = y0 + ly;
            const int gx = x0 + lx;
            float gval = 0.0f;
            if ((unsigned)gy < 1024u && (unsigned)gx < 1024u) {
                const size_t off = (size_t)gy * 1024u + (size_t)gx;
                const float r = imgb[off];
                const float g = imgb[off + 1024u * 1024u];
                const float bb = imgb[off + 2u * 1024u * 1024u];
                gval = (r * 0.299f + g * 0.587f) + bb * 0.114f;
            }
            tile[ly][lx] = gval;
        }
        __syncthreads();

        const int tx  = tid & 63;
        const int ty0 = tid >> 6;   // 0..3
        #pragma unroll
        for (int rr = 0; rr < TY / 4; ++rr) {
            const int ly = ty0 + 4 * rr;         // pixel row in tile
            const float c = tile[ly + 1][tx + 1];
            // bit i set iff (neighbor - center >= 0) <=> neighbor >= center
            unsigned code =
                (tile[ly    ][tx + 2] >= c ? 1u   : 0u) |  // (y-1, x+1)
                (tile[ly + 1][tx + 2] >= c ? 2u   : 0u) |  // (y,   x+1)
                (tile[ly + 2][tx + 2] >= c ? 4u   : 0u) |  // (y+1, x+1)
                (tile[ly + 2][tx + 1] >= c ? 8u   : 0u) |  // (y+1, x  )
                (tile[ly + 2][tx    ] >= c ? 16u  : 0u) |  // (y+1, x-1)
                (tile[ly + 1][tx    ] >= c ? 32u  : 0u) |  // (y,   x-1)
                (tile[ly    ][tx    ] >= c ? 64u  : 0u) |  // (y-1, x-1)
                (tile[ly    ][tx + 1] >= c ? 128u : 0u);   // (y-1, x  )
            atomicAdd(&s_hist[code], 1u);
        }
    }
    __syncthreads();
    atomicAdd(&g_hist[tid], s_hist[tid]);
}

__global__ __launch_bounds__(256) void lbp_finalize(
        const unsigned* __restrict__ g_hist, float* __restrict__ out) {
    __shared__ float red[256];
    const int i = threadIdx.x;
    const float h = (float)g_hist[i];
    red[i] = h;
    __syncthreads();
    #pragma unroll
    for (int s = 128; s > 0; s >>= 1) {
        if (i < s) red[i] += red[i + s];
        __syncthreads();
    }
    const float mean = red[0] * (1.0f / 256.0f);
    __syncthreads();
    const float d = h - mean;
    red[i] = d * d;
    __syncthreads();
    #pragma unroll
    for (int s = 128; s > 0; s >>= 1) {
        if (i < s) red[i] += red[i + s];
        __syncthreads();
    }
    const float stdv = sqrtf(red[0] * (1.0f / 255.0f));
    out[i] = d / stdv;
}

extern "C" void kernel_launch(void* const* d_in, const int* in_sizes, int n_in,
                              void* d_out, int out_size, void* d_ws, size_t ws_size,
                              hipStream_t stream) {
    const float* img = (const float*)d_in[0];
    unsigned* g_hist = (unsigned*)d_ws;   // 256 * 4 bytes of scratch
    float* out = (float*)d_out;

    lbp_zero_hist<<<1, 256, 0, stream>>>(g_hist);
    lbp_hist_kernel<<<NBLOCKS, 256, 0, stream>>>(img, g_hist);
    lbp_finalize<<<1, 256, 0, stream>>>(g_hist, out);
}

// Round 2
// 284.529 us; speedup vs baseline: 1.0833x; 1.0833x over previous
//
#include <hip/hip_runtime.h>

#define TX 64
#define TY 32
#define TILE_H 34            // TY + 2 halo rows
#define TILE_W 72            // 66 needed, padded to 72 for float4-aligned staging
#define NTX (1024 / TX)      // 16
#define NTY (1024 / TY)      // 32
#define NBATCH 16
#define NTILES (NTX * NTY * NBATCH)  // 8192
#define NBLOCKS 2048                 // 4 tiles/block, 8 blocks/CU
#define NHIST 8                      // global histogram copies (flush contention /8)

__global__ void lbp_zero_hist(unsigned* __restrict__ g_hist) {
    g_hist[blockIdx.x * 256 + threadIdx.x] = 0u;
}

__global__ __launch_bounds__(256) void lbp_hist_kernel(
        const float* __restrict__ img, unsigned* __restrict__ g_hist) {
    __shared__ __align__(16) float tile[TILE_H][TILE_W];   // 9792 B
    __shared__ unsigned s_hist[4][256];                    // 4096 B, one copy per wave
    const int tid = threadIdx.x;
    const int wv  = tid >> 6;        // wave id 0..3
    #pragma unroll
    for (int w = 0; w < 4; ++w) s_hist[w][tid] = 0u;

    const int tx = tid & 63;         // pixel column within tile
    const int ry = wv * 8;           // first pixel row handled by this thread

    for (int t = blockIdx.x; t < NTILES; t += NBLOCKS) {
        const int bx  = t % NTX;
        const int rem = t / NTX;
        const int by  = rem % NTY;
        const int b   = rem / NTY;
        const int y0  = by * TY - 1;            // global row of tile row 0
        const int xq0 = bx * TX - 4;            // global col of tile col 0 (aligned)
        const float* imgb = img + (size_t)b * 3u * 1024u * 1024u;

        __syncthreads();   // tile reused across grid-stride iterations

        // ---- stage gray tile: 34 rows x 18 aligned float4 quads ----
        for (int it = tid; it < TILE_H * 18; it += 256) {
            const int row = it / 18;
            const int q   = it - row * 18;
            const int gy  = y0 + row;
            const int gxq = xq0 + (q << 2);
            float4 gv = make_float4(0.f, 0.f, 0.f, 0.f);
            if ((unsigned)gy < 1024u) {
                const float* rowp = imgb + (size_t)gy * 1024u;
                if ((unsigned)gxq <= 1020u) {   // fully in-bounds quad (common case)
                    const float4 r4 = *(const float4*)(rowp + gxq);
                    const float4 g4 = *(const float4*)(rowp + 1048576u + gxq);
                    const float4 b4 = *(const float4*)(rowp + 2097152u + gxq);
                    gv.x = (r4.x * 0.299f + g4.x * 0.587f) + b4.x * 0.114f;
                    gv.y = (r4.y * 0.299f + g4.y * 0.587f) + b4.y * 0.114f;
                    gv.z = (r4.z * 0.299f + g4.z * 0.587f) + b4.z * 0.114f;
                    gv.w = (r4.w * 0.299f + g4.w * 0.587f) + b4.w * 0.114f;
                } else {                         // edge quad: per-element masked
                    #pragma unroll
                    for (int k = 0; k < 4; ++k) {
                        const int gx = gxq + k;
                        if ((unsigned)gx < 1024u) {
                            const float r  = rowp[gx];
                            const float g  = rowp[1048576u + gx];
                            const float bb = rowp[2097152u + gx];
                            ((float*)&gv)[k] = (r * 0.299f + g * 0.587f) + bb * 0.114f;
                        }
                    }
                }
            }
            *(float4*)&tile[row][q << 2] = gv;
        }
        __syncthreads();

        // ---- compute 8 contiguous pixel rows with 3x3 register rolling window ----
        // pixel (py, tx): center tile[py+1][tx+4]; cols tx+3..tx+5, rows py..py+2
        float c00 = tile[ry    ][tx + 3], c01 = tile[ry    ][tx + 4], c02 = tile[ry    ][tx + 5];
        float c10 = tile[ry + 1][tx + 3], c11 = tile[ry + 1][tx + 4], c12 = tile[ry + 1][tx + 5];
        #pragma unroll
        for (int p = 0; p < 8; ++p) {
            const float c20 = tile[ry + p + 2][tx + 3];
            const float c21 = tile[ry + p + 2][tx + 4];
            const float c22 = tile[ry + p + 2][tx + 5];
            const unsigned code =
                (c02 >= c11 ? 1u   : 0u) |   // (y-1, x+1)
                (c12 >= c11 ? 2u   : 0u) |   // (y,   x+1)
                (c22 >= c11 ? 4u   : 0u) |   // (y+1, x+1)
                (c21 >= c11 ? 8u   : 0u) |   // (y+1, x  )
                (c20 >= c11 ? 16u  : 0u) |   // (y+1, x-1)
                (c10 >= c11 ? 32u  : 0u) |   // (y,   x-1)
                (c00 >= c11 ? 64u  : 0u) |   // (y-1, x-1)
                (c01 >= c11 ? 128u : 0u);    // (y-1, x  )
            atomicAdd(&s_hist[wv][code], 1u);
            c00 = c10; c01 = c11; c02 = c12;
            c10 = c20; c11 = c21; c12 = c22;
        }
    }

    __syncthreads();
    const unsigned total = s_hist[0][tid] + s_hist[1][tid] + s_hist[2][tid] + s_hist[3][tid];
    atomicAdd(&g_hist[((blockIdx.x & (NHIST - 1)) << 8) + tid], total);
}

__global__ __launch_bounds__(256) void lbp_finalize(
        const unsigned* __restrict__ g_hist, float* __restrict__ out) {
    __shared__ float red[256];
    const int i = threadIdx.x;
    unsigned hv = 0u;
    #pragma unroll
    for (int c = 0; c < NHIST; ++c) hv += g_hist[(c << 8) + i];
    const float h = (float)hv;
    red[i] = h;
    __syncthreads();
    #pragma unroll
    for (int s = 128; s > 0; s >>= 1) {
        if (i < s) red[i] += red[i + s];
        __syncthreads();
    }
    const float mean = red[0] * (1.0f / 256.0f);
    __syncthreads();
    const float d = h - mean;
    red[i] = d * d;
    __syncthreads();
    #pragma unroll
    for (int s = 128; s > 0; s >>= 1) {
        if (i < s) red[i] += red[i + s];
        __syncthreads();
    }
    const float stdv = sqrtf(red[0] * (1.0f / 255.0f));
    out[i] = d / stdv;
}

extern "C" void kernel_launch(void* const* d_in, const int* in_sizes, int n_in,
                              void* d_out, int out_size, void* d_ws, size_t ws_size,
                              hipStream_t stream) {
    const float* img = (const float*)d_in[0];
    unsigned* g_hist = (unsigned*)d_ws;   // NHIST * 256 * 4 bytes of scratch
    float* out = (float*)d_out;

    lbp_zero_hist<<<NHIST, 256, 0, stream>>>(g_hist);
    lbp_hist_kernel<<<NBLOCKS, 256, 0, stream>>>(img, g_hist);
    lbp_finalize<<<1, 256, 0, stream>>>(g_hist, out);
}